// Round 6
// baseline (134.342 us; speedup 1.0000x reference)
//
#include <hip/hip_runtime.h>
#include <hip/hip_bf16.h>
#include <cstddef>
#include <cstdint>

#define B_ 8
#define H_ 8
#define N_ 512
#define K_ 16
#define NN_ (N_*N_)

static constexpr float ALPHA_C = 0.001f;

typedef float f32x4 __attribute__((ext_vector_type(4)));

// -------------------------------------------------------------------------
// Kernel 1 (prep): per (b,n) compute v = exp(-A) mu and q = 0.5*||v||^2
// via Taylor MATVEC series only (no matmuls, no Om materialization).
// Wave = 4 matrices; lane = m*16 + r holds row r of -A in 16 VGPRs.
// Per matvec: 16 FMA + 1 ds_write_b32 + 4 broadcast ds_read_b128.
// Degree d = ceil(2.2*theta)+6 (wave-max -> uniform), theta = ||A||_F.
// -------------------------------------------------------------------------
__global__ __launch_bounds__(256) void prep_kernel(
    const float* __restrict__ mu, const float* __restrict__ phi,
    const float* __restrict__ gen, float* __restrict__ v,
    float* __restrict__ q)
{
    __shared__ __align__(16) float xb[4][4][16];   // [wave][m][16]

    const int tid = threadIdx.x;
    const int w = tid >> 6, lane = tid & 63;
    const int m = lane >> 4, r = lane & 15;
    const int bn = (blockIdx.x << 4) | (w << 2) | m;

    // row r of -A = -(p0*G0 + p1*G1 + p2*G2)
    const float p0 = phi[bn*3+0], p1 = phi[bn*3+1], p2 = phi[bn*3+2];
    float row[16];
    #pragma unroll
    for (int i = 0; i < 4; ++i) {
        const f32x4 g0 = *(const f32x4*)&gen[r*16 + 4*i];
        const f32x4 g1 = *(const f32x4*)&gen[256 + r*16 + 4*i];
        const f32x4 g2 = *(const f32x4*)&gen[512 + r*16 + 4*i];
        row[4*i+0] = -(p0*g0.x + p1*g1.x + p2*g2.x);
        row[4*i+1] = -(p0*g0.y + p1*g1.y + p2*g2.y);
        row[4*i+2] = -(p0*g0.z + p1*g1.z + p2*g2.z);
        row[4*i+3] = -(p0*g0.w + p1*g1.w + p2*g2.w);
    }

    // theta = ||A||_F per matrix (reduce over the 16-lane group)
    float t = 0.f;
    #pragma unroll
    for (int k = 0; k < 16; ++k) t = fmaf(row[k], row[k], t);
    #pragma unroll
    for (int msk = 1; msk <= 8; msk <<= 1) t += __shfl_xor(t, msk, 64);
    float theta = sqrtf(t);
    // wave-uniform degree: max over the 4 matrices
    float tm = theta;
    tm = fmaxf(tm, __shfl_xor(tm, 16, 64));
    tm = fmaxf(tm, __shfl_xor(tm, 32, 64));
    int d = (int)ceilf(2.2f * tm) + 6;
    if (d > 30) d = 30;

    // series: x0 = mu; x_{n+1} = (-A) x_n / (n+1); v = sum x_n
    float x = mu[bn*16 + r];
    float S = x;
    xb[w][m][r] = x;
    __builtin_amdgcn_wave_barrier();

    for (int n = 1; n <= d; ++n) {
        const f32x4 x0 = *(const f32x4*)&xb[w][m][0];
        const f32x4 x1 = *(const f32x4*)&xb[w][m][4];
        const f32x4 x2 = *(const f32x4*)&xb[w][m][8];
        const f32x4 x3 = *(const f32x4*)&xb[w][m][12];
        float y;
        y = row[0]*x0.x;            y = fmaf(row[1],  x0.y, y);
        y = fmaf(row[2],  x0.z, y); y = fmaf(row[3],  x0.w, y);
        y = fmaf(row[4],  x1.x, y); y = fmaf(row[5],  x1.y, y);
        y = fmaf(row[6],  x1.z, y); y = fmaf(row[7],  x1.w, y);
        y = fmaf(row[8],  x2.x, y); y = fmaf(row[9],  x2.y, y);
        y = fmaf(row[10], x2.z, y); y = fmaf(row[11], x2.w, y);
        y = fmaf(row[12], x3.x, y); y = fmaf(row[13], x3.y, y);
        y = fmaf(row[14], x3.z, y); y = fmaf(row[15], x3.w, y);
        y *= (1.0f / (float)n);
        S += y;
        __builtin_amdgcn_wave_barrier();
        xb[w][m][r] = y;
        __builtin_amdgcn_wave_barrier();
    }

    // v write: addr = blk*256 + w*64 + m*16 + r -> coalesced per wave
    v[(size_t)bn * 16 + r] = S;

    // q = 0.5*||v||^2
    float qp = S * S;
    #pragma unroll
    for (int msk = 1; msk <= 8; msk <<= 1) qp += __shfl_xor(qp, msk, 64);
    if (r == 0) q[bn] = 0.5f * qp;
}

// -------------------------------------------------------------------------
// Kernel 2: memory-bound pass over beta (unchanged main loop). Epilogue:
// S = Om_i * gvec = coef*mu_i - exp(A_i)*wc  (orthogonality: Om v = mu),
// with exp(A_i)*wc computed by an in-wave Taylor matvec series in strip
// layout (r=lane>>2, ci=lane&3), ~4 DS ops per matvec.
// -------------------------------------------------------------------------
__global__ __launch_bounds__(256, 4) void grad_kernel(
    const float* __restrict__ mu, const float* __restrict__ beta,
    const float* __restrict__ mu_prior, const float* __restrict__ lrp,
    const float* __restrict__ phi, const float* __restrict__ gen,
    const float* __restrict__ v, const float* __restrict__ q,
    float* __restrict__ out)
{
    __shared__ __align__(16) float v_t[16 * 516];  // 16 x 129 f4 (pad 1 f4)
    __shared__ __align__(16) f32x4 q4[128];
    __shared__ __align__(16) float eb[4][16];

    const int blk = blockIdx.x;          // 0..1023
    const int b   = blk >> 7;
    const int i0  = (blk & 127) << 2;
    const int tid = threadIdx.x;
    const int wid = tid >> 6, lane = tid & 63;

    // stage v[b] transposed into LDS (dwordx4 global reads)
    const float* vb = v + (size_t)b * N_ * K_;
    for (int f4 = tid; f4 < (N_ * K_) / 4; f4 += 256) {
        const f32x4 tq = *(const f32x4*)&vb[f4 << 2];
        const int j  = f4 >> 2;
        const int k0 = (f4 & 3) << 2;
        v_t[(k0+0) * 516 + j] = tq.x;
        v_t[(k0+1) * 516 + j] = tq.y;
        v_t[(k0+2) * 516 + j] = tq.z;
        v_t[(k0+3) * 516 + j] = tq.w;
    }
    const f32x4* qb4 = (const f32x4*)(q + (size_t)b * N_);
    if (tid < 128) q4[tid] = qb4[tid];
    __syncthreads();

    const int i = i0 + wid;

    float vi[16];
    #pragma unroll
    for (int k = 0; k < 16; ++k) vi[k] = v_t[k * 516 + i];   // broadcast
    const float qi = ((const float*)q4)[i];

    float w1[16], w2[16];
    #pragma unroll
    for (int k = 0; k < 16; ++k) { w1[k] = 0.f; w2[k] = 0.f; }
    float sacc = 0.f, R = 0.f;

    const size_t betaBase = (((size_t)b * H_) * N_ + i) * N_;

    #pragma unroll 1
    for (int p = 0; p < 2; ++p) {
        const int j0 = (lane << 2) | (p << 8);

        const float* bp = beta + betaBase + j0;
        float rx = 0.f, ry = 0.f, rz = 0.f, rw = 0.f;
        #pragma unroll
        for (int h = 0; h < H_; ++h) {
            const f32x4 bt = __builtin_nontemporal_load(
                (const f32x4*)(bp + (size_t)h * NN_));
            rx += bt.x; ry += bt.y; rz += bt.z; rw += bt.w;
        }
        rx *= 0.125f; ry *= 0.125f; rz *= 0.125f; rw *= 0.125f;

        float d0 = 0.f, d1 = 0.f, d2 = 0.f, d3 = 0.f;
        #pragma unroll
        for (int k = 0; k < 16; ++k) {
            const f32x4 vj = *(const f32x4*)&v_t[k * 516 + j0];
            d0 = fmaf(vi[k], vj.x, d0);
            d1 = fmaf(vi[k], vj.y, d1);
            d2 = fmaf(vi[k], vj.z, d2);
            d3 = fmaf(vi[k], vj.w, d3);
        }
        const f32x4 qj = q4[lane | (p << 6)];
        const float rkl0 = rx * (qi + qj.x - d0);
        const float rkl1 = ry * (qi + qj.y - d1);
        const float rkl2 = rz * (qi + qj.z - d2);
        const float rkl3 = rw * (qi + qj.w - d3);
        sacc += (rkl0 + rkl1) + (rkl2 + rkl3);
        R    += (rx + ry) + (rz + rw);

        #pragma unroll
        for (int k = 0; k < 16; ++k) {
            const f32x4 vj = *(const f32x4*)&v_t[k * 516 + j0];
            float a1 = fmaf(rx, vj.x, w1[k]);
            a1 = fmaf(ry, vj.y, a1);
            a1 = fmaf(rz, vj.z, a1);
            w1[k] = fmaf(rw, vj.w, a1);
            float a2 = fmaf(rkl0, vj.x, w2[k]);
            a2 = fmaf(rkl1, vj.y, a2);
            a2 = fmaf(rkl2, vj.z, a2);
            w2[k] = fmaf(rkl3, vj.w, a2);
        }
    }

    // ---- stage A: butterfly the two scalars ----
    #pragma unroll
    for (int off = 32; off > 0; off >>= 1) {
        sacc += __shfl_xor(sacc, off, 64);
        R    += __shfl_xor(R,    off, 64);
    }
    const float oms  = 1.0f - sacc;
    const float coef = oms * R + sacc;

    // ---- stage B: wc = (1-s)*w1 + w2 ----
    float wc[16];
    #pragma unroll
    for (int k = 0; k < 16; ++k) wc[k] = fmaf(oms, w1[k], w2[k]);

    // ---- stage C: halving exchange; lane ends with sum of wc[c],
    //      c = lane>>2 ----
    {
        #pragma unroll
        for (int k = 0; k < 8; ++k) {             // mask 32, keep 8
            const bool up = (lane & 32) != 0;
            const float send = up ? wc[k] : wc[k + 8];
            const float recv = __shfl_xor(send, 32, 64);
            wc[k] = (up ? wc[k + 8] : wc[k]) + recv;
        }
        #pragma unroll
        for (int k = 0; k < 4; ++k) {             // mask 16, keep 4
            const bool up = (lane & 16) != 0;
            const float send = up ? wc[k] : wc[k + 4];
            const float recv = __shfl_xor(send, 16, 64);
            wc[k] = (up ? wc[k + 4] : wc[k]) + recv;
        }
        #pragma unroll
        for (int k = 0; k < 2; ++k) {             // mask 8, keep 2
            const bool up = (lane & 8) != 0;
            const float send = up ? wc[k] : wc[k + 2];
            const float recv = __shfl_xor(send, 8, 64);
            wc[k] = (up ? wc[k + 2] : wc[k]) + recv;
        }
        {                                          // mask 4, keep 1
            const bool up = (lane & 4) != 0;
            const float send = up ? wc[0] : wc[1];
            const float recv = __shfl_xor(send, 4, 64);
            wc[0] = (up ? wc[1] : wc[0]) + recv;
        }
        wc[0] += __shfl_xor(wc[0], 2, 64);
        wc[0] += __shfl_xor(wc[0], 1, 64);
    }

    // ---- stage D: S2 = exp(A_i) * wc via Taylor matvec series ----
    const int r2 = lane >> 2, ci = lane & 3;

    if (ci == 0) eb[wid][r2] = wc[0];     // r2 == c for ci==0 lanes
    __builtin_amdgcn_wave_barrier();

    // build +A_i strip: A[r2][4ci..4ci+3]
    const float* ph = phi + ((size_t)b * N_ + i) * 3;
    const float pp0 = ph[0], pp1 = ph[1], pp2 = ph[2];
    const int go = r2 * 16 + (ci << 2);
    const f32x4 g0 = *(const f32x4*)&gen[go];
    const f32x4 g1 = *(const f32x4*)&gen[256 + go];
    const f32x4 g2 = *(const f32x4*)&gen[512 + go];
    f32x4 Ast;
    Ast.x = pp0*g0.x + pp1*g1.x + pp2*g2.x;
    Ast.y = pp0*g0.y + pp1*g1.y + pp2*g2.y;
    Ast.z = pp0*g0.z + pp1*g1.z + pp2*g2.z;
    Ast.w = pp0*g0.w + pp1*g1.w + pp2*g2.w;

    float tt = Ast.x*Ast.x + Ast.y*Ast.y + Ast.z*Ast.z + Ast.w*Ast.w;
    #pragma unroll
    for (int msk = 1; msk <= 32; msk <<= 1) tt += __shfl_xor(tt, msk, 64);
    int d2 = (int)ceilf(2.2f * sqrtf(tt)) + 6;
    if (d2 > 30) d2 = 30;

    float S2 = eb[wid][r2];                       // x0[r]
    f32x4 xs = *(const f32x4*)&eb[wid][ci << 2];  // x0 strip

    for (int n = 1; n <= d2; ++n) {
        float y = Ast.x * xs.x;
        y = fmaf(Ast.y, xs.y, y);
        y = fmaf(Ast.z, xs.z, y);
        y = fmaf(Ast.w, xs.w, y);
        y += __shfl_xor(y, 1, 64);
        y += __shfl_xor(y, 2, 64);                // all 4 lanes of row r2
        y *= (1.0f / (float)n);
        S2 += y;
        __builtin_amdgcn_wave_barrier();
        if (ci == 0) eb[wid][r2] = y;
        __builtin_amdgcn_wave_barrier();
        xs = *(const f32x4*)&eb[wid][ci << 2];
    }

    if (ci == 0) {
        const float lr = lrp[0];
        const size_t oi = ((size_t)b * N_ + i) * 16 + r2;
        const float m0 = mu[oi], mp = mu_prior[oi];
        // S = coef*mu - S2;  out = m0 - lr*(ALPHA*(m0-mp) + S)
        out[oi] = m0 - lr * (ALPHA_C * (m0 - mp) + coef * m0 - S2);
    }
}

// -------------------------------------------------------------------------
extern "C" void kernel_launch(void* const* d_in, const int* in_sizes, int n_in,
                              void* d_out, int out_size, void* d_ws, size_t ws_size,
                              hipStream_t stream)
{
    const float* mu   = (const float*)d_in[0];
    const float* beta = (const float*)d_in[1];
    const float* mup  = (const float*)d_in[2];
    const float* phi  = (const float*)d_in[3];
    const float* gen  = (const float*)d_in[4];
    const float* lr   = (const float*)d_in[5];
    float* out = (float*)d_out;

    float* v = (float*)d_ws;                        // 4096*16 floats
    float* q = v + (size_t)4096 * 16;               // 4096

    prep_kernel<<<256, 256, 0, stream>>>(mu, phi, gen, v, q);
    grad_kernel<<<B_ * (N_ / 4), 256, 0, stream>>>(mu, beta, mup, lr,
                                                   phi, gen, v, q, out);
}